// Round 5
// baseline (430.670 us; speedup 1.0000x reference)
//
#include <hip/hip_runtime.h>
#include <hip/hip_bf16.h>

#define N_NODES 50000
#define SEQ 12
#define CH 128
#define BS 4
#define TILE 64
#define PAD_ROW 132   // floats per LDS row (pad 128 -> 132 to break bank-conflict stride)

typedef short bf16x8 __attribute__((ext_vector_type(8)));
typedef float f32x4 __attribute__((ext_vector_type(4)));

__global__ __launch_bounds__(256) void gated_spiral_kernel(
    const float* __restrict__ x,
    const int* __restrict__ indices,
    const float* __restrict__ weight,
    const float* __restrict__ gate_w,
    const float* __restrict__ gate_b,
    float* __restrict__ out)
{
    __shared__ float spiral[TILE * PAD_ROW];   // 33792 B

    const int tile = blockIdx.x;
    const int b = blockIdx.y;
    const int tid = threadIdx.x;
    const int node0 = tile * TILE;

    const float* xb = x + (size_t)b * N_NODES * CH;

    // ---- Phase 1: spiral gather + weighted reduce (4 threads/node, 32 ch each, fp32) ----
    {
        const int v = node0 + (tid >> 2);
        const int vc = v < N_NODES ? v : N_NODES - 1;
        const int q = tid & 3;

        int   idxv[SEQ];
        float wf[SEQ];
        const int*   ip = indices + (size_t)vc * SEQ;
        const float* wp = weight  + (size_t)vc * SEQ;
        #pragma unroll
        for (int s = 0; s < SEQ; ++s) {
            int t = ip[s];
            t = t < 0 ? 0 : t;
            idxv[s] = t >= N_NODES ? N_NODES - 1 : t;
            wf[s] = wp[s];
        }

        float acc[32];
        #pragma unroll
        for (int i = 0; i < 32; ++i) acc[i] = 0.f;

        #pragma unroll
        for (int s = 0; s < SEQ; ++s) {
            const float* row = xb + (size_t)idxv[s] * CH + q * 4;
            const float ws = wf[s];
            #pragma unroll
            for (int j = 0; j < 8; ++j) {
                float4 d = *(const float4*)(row + j * 16);   // lanes q=0..3 contiguous 64B
                acc[j*4+0] += ws * d.x;
                acc[j*4+1] += ws * d.y;
                acc[j*4+2] += ws * d.z;
                acc[j*4+3] += ws * d.w;
            }
        }

        const int vl = tid >> 2;
        #pragma unroll
        for (int j = 0; j < 8; ++j)
            *(float4*)(spiral + vl * PAD_ROW + j * 16 + q * 4) =
                make_float4(acc[j*4+0], acc[j*4+1], acc[j*4+2], acc[j*4+3]);
    }
    __syncthreads();

    // ---- Phase 2: gate GEMM via MFMA 16x16x32_bf16 (fp32 cast to bf16; error << threshold) ----
    {
        const int wave = tid >> 6;
        const int lane = tid & 63;
        const int m = lane & 15;
        const int quad = lane >> 4;

        int arow_node = node0 + wave * 16 + m;
        if (arow_node >= N_NODES) arow_node = N_NODES - 1;
        const float* ap = xb + (size_t)arow_node * CH + quad * 8;

        // A[m = lane&15][k = quad*8 + j]
        bf16x8 afrag[4];
        #pragma unroll
        for (int kk = 0; kk < 4; ++kk) {
            float4 lo = *(const float4*)(ap + kk * 32);
            float4 hi = *(const float4*)(ap + kk * 32 + 4);
            union { bf16x8 v; __hip_bfloat16 h[8]; } af;
            af.h[0] = __float2bfloat16(lo.x); af.h[1] = __float2bfloat16(lo.y);
            af.h[2] = __float2bfloat16(lo.z); af.h[3] = __float2bfloat16(lo.w);
            af.h[4] = __float2bfloat16(hi.x); af.h[5] = __float2bfloat16(hi.y);
            af.h[6] = __float2bfloat16(hi.z); af.h[7] = __float2bfloat16(hi.w);
            afrag[kk] = af.v;
        }

        float gb[8];
        #pragma unroll
        for (int t = 0; t < 8; ++t)
            gb[t] = gate_b[t * 16 + m];

        #pragma unroll
        for (int t = 0; t < 8; ++t) {
            f32x4 c = {0.f, 0.f, 0.f, 0.f};
            // B[k = quad*8+j][n = lane&15] = gate_w[n_abs][k] -> contiguous row read
            const float* bp = gate_w + (size_t)(t * 16 + m) * CH + quad * 8;
            #pragma unroll
            for (int kk = 0; kk < 4; ++kk) {
                float4 lo = *(const float4*)(bp + kk * 32);
                float4 hi = *(const float4*)(bp + kk * 32 + 4);
                union { bf16x8 v; __hip_bfloat16 h[8]; } bf;
                bf.h[0] = __float2bfloat16(lo.x); bf.h[1] = __float2bfloat16(lo.y);
                bf.h[2] = __float2bfloat16(lo.z); bf.h[3] = __float2bfloat16(lo.w);
                bf.h[4] = __float2bfloat16(hi.x); bf.h[5] = __float2bfloat16(hi.y);
                bf.h[6] = __float2bfloat16(hi.z); bf.h[7] = __float2bfloat16(hi.w);
                c = __builtin_amdgcn_mfma_f32_16x16x32_bf16(afrag[kk], bf.v, c, 0, 0, 0);
            }
            // D: col = lane&15 (out channel), row = quad*4 + reg (node within wave's 16)
            #pragma unroll
            for (int reg = 0; reg < 4; ++reg) {
                const int r = wave * 16 + quad * 4 + reg;
                const int col = t * 16 + m;
                const float sp = spiral[r * PAD_ROW + col];
                spiral[r * PAD_ROW + col] = sp * (c[reg] + gb[t]);
            }
        }
    }
    __syncthreads();

    // ---- Phase 3: coalesced FP32 store (reference output dtype is float32) ----
    {
        #pragma unroll
        for (int p = 0; p < 8; ++p) {
            const int seg = p * 256 + tid;      // 2048 segments of 4 floats
            const int row = seg >> 5;
            const int c4 = (seg & 31) * 4;
            const int node = node0 + row;
            if (node < N_NODES) {
                float4 v = *(const float4*)(spiral + row * PAD_ROW + c4);
                *(float4*)(out + ((size_t)b * N_NODES + node) * CH + c4) = v;
            }
        }
    }
}

extern "C" void kernel_launch(void* const* d_in, const int* in_sizes, int n_in,
                              void* d_out, int out_size, void* d_ws, size_t ws_size,
                              hipStream_t stream) {
    const float* x       = (const float*)d_in[0];
    const int*   indices = (const int*)d_in[1];
    const float* weight  = (const float*)d_in[2];
    const float* gate_w  = (const float*)d_in[3];
    const float* gate_b  = (const float*)d_in[4];
    float*       out     = (float*)d_out;

    dim3 grid((N_NODES + TILE - 1) / TILE, BS);
    gated_spiral_kernel<<<grid, dim3(256), 0, stream>>>(x, indices, weight, gate_w, gate_b, out);
}

// Round 6
// 346.144 us; speedup vs baseline: 1.2442x; 1.2442x over previous
//
#include <hip/hip_runtime.h>
#include <hip/hip_bf16.h>

#define N_NODES 50000
#define SEQ 12
#define CH 128
#define BS 4
#define TILE 64
#define PAD_ROW 132   // floats per LDS row (pad 128 -> 132 to break bank-conflict stride)

typedef short bf16x8 __attribute__((ext_vector_type(8)));
typedef float f32x4 __attribute__((ext_vector_type(4)));

// ---------------- Kernel A: fp32 -> bf16 conversion of x and gate_w ----------------
__global__ __launch_bounds__(256) void convert_kernel(
    const float* __restrict__ x,
    const float* __restrict__ gate_w,
    __hip_bfloat16* __restrict__ xb,
    __hip_bfloat16* __restrict__ gwb)
{
    const size_t i = (size_t)blockIdx.x * 256 + threadIdx.x;   // one thread per 8 elements
    const size_t n8 = (size_t)BS * N_NODES * CH / 8;           // 3,200,000
    if (i < n8) {
        float4 lo = *(const float4*)(x + i * 8);
        float4 hi = *(const float4*)(x + i * 8 + 4);
        union { bf16x8 v; __hip_bfloat16 h[8]; } o;
        o.h[0] = __float2bfloat16(lo.x); o.h[1] = __float2bfloat16(lo.y);
        o.h[2] = __float2bfloat16(lo.z); o.h[3] = __float2bfloat16(lo.w);
        o.h[4] = __float2bfloat16(hi.x); o.h[5] = __float2bfloat16(hi.y);
        o.h[6] = __float2bfloat16(hi.z); o.h[7] = __float2bfloat16(hi.w);
        *(bf16x8*)((unsigned short*)xb + i * 8) = o.v;
    }
    if (i < (size_t)CH * CH / 8) {
        float4 lo = *(const float4*)(gate_w + i * 8);
        float4 hi = *(const float4*)(gate_w + i * 8 + 4);
        union { bf16x8 v; __hip_bfloat16 h[8]; } o;
        o.h[0] = __float2bfloat16(lo.x); o.h[1] = __float2bfloat16(lo.y);
        o.h[2] = __float2bfloat16(lo.z); o.h[3] = __float2bfloat16(lo.w);
        o.h[4] = __float2bfloat16(hi.x); o.h[5] = __float2bfloat16(hi.y);
        o.h[6] = __float2bfloat16(hi.z); o.h[7] = __float2bfloat16(hi.w);
        *(bf16x8*)((unsigned short*)gwb + i * 8) = o.v;
    }
}

// ---------------- Kernel B: gather from bf16 x (half the bytes/requests) ----------------
__global__ __launch_bounds__(256) void gated_spiral_bf16_kernel(
    const __hip_bfloat16* __restrict__ xb_all,
    const int* __restrict__ indices,
    const float* __restrict__ weight,
    const __hip_bfloat16* __restrict__ gwb,
    const float* __restrict__ gate_b,
    float* __restrict__ out)
{
    __shared__ float spiral[TILE * PAD_ROW];   // 33792 B

    const int tile = blockIdx.x;
    const int b = blockIdx.y;
    const int tid = threadIdx.x;
    const int node0 = tile * TILE;

    const unsigned short* xbb = (const unsigned short*)xb_all + (size_t)b * N_NODES * CH;

    // ---- Phase 1: spiral gather + weighted reduce (4 threads/node, 32 ch each) ----
    {
        const int v = node0 + (tid >> 2);
        const int vc = v < N_NODES ? v : N_NODES - 1;
        const int q = tid & 3;

        int   idxv[SEQ];
        float wf[SEQ];
        const int*   ip = indices + (size_t)vc * SEQ;
        const float* wp = weight  + (size_t)vc * SEQ;
        #pragma unroll
        for (int s = 0; s < SEQ; ++s) {
            int t = ip[s];
            t = t < 0 ? 0 : t;
            idxv[s] = t >= N_NODES ? N_NODES - 1 : t;
            wf[s] = wp[s];
        }

        float acc[32];
        #pragma unroll
        for (int i = 0; i < 32; ++i) acc[i] = 0.f;

        #pragma unroll
        for (int s = 0; s < SEQ; ++s) {
            const unsigned short* row = xbb + (size_t)idxv[s] * CH;
            const float ws = wf[s];
            #pragma unroll
            for (int j = 0; j < 4; ++j) {
                // lanes q=0..3 read contiguous 64B: row bytes [j*64 + q*16 .. +16)
                uint4 d = *(const uint4*)(row + j * 32 + q * 8);
                unsigned int u0 = d.x, u1 = d.y, u2 = d.z, u3 = d.w;
                acc[j*8+0] += ws * __uint_as_float(u0 << 16);
                acc[j*8+1] += ws * __uint_as_float(u0 & 0xFFFF0000u);
                acc[j*8+2] += ws * __uint_as_float(u1 << 16);
                acc[j*8+3] += ws * __uint_as_float(u1 & 0xFFFF0000u);
                acc[j*8+4] += ws * __uint_as_float(u2 << 16);
                acc[j*8+5] += ws * __uint_as_float(u2 & 0xFFFF0000u);
                acc[j*8+6] += ws * __uint_as_float(u3 << 16);
                acc[j*8+7] += ws * __uint_as_float(u3 & 0xFFFF0000u);
            }
        }

        // thread q owns channels {j*32 + q*8 + k : j=0..3, k=0..7}
        const int vl = tid >> 2;
        #pragma unroll
        for (int j = 0; j < 4; ++j) {
            float* dst = spiral + vl * PAD_ROW + j * 32 + q * 8;
            *(float4*)(dst)     = make_float4(acc[j*8+0], acc[j*8+1], acc[j*8+2], acc[j*8+3]);
            *(float4*)(dst + 4) = make_float4(acc[j*8+4], acc[j*8+5], acc[j*8+6], acc[j*8+7]);
        }
    }
    __syncthreads();

    // ---- Phase 2: gate GEMM via MFMA 16x16x32_bf16, fragments loaded directly as bf16 ----
    {
        const int wave = tid >> 6;
        const int lane = tid & 63;
        const int m = lane & 15;
        const int quad = lane >> 4;

        int arow_node = node0 + wave * 16 + m;
        if (arow_node >= N_NODES) arow_node = N_NODES - 1;
        const unsigned short* ap = xbb + (size_t)arow_node * CH + quad * 8;

        // A[m = lane&15][k = quad*8 + j] -> contiguous 8 bf16 = one 16B load
        bf16x8 afrag[4];
        #pragma unroll
        for (int kk = 0; kk < 4; ++kk)
            afrag[kk] = *(const bf16x8*)(ap + kk * 32);

        float gb[8];
        #pragma unroll
        for (int t = 0; t < 8; ++t)
            gb[t] = gate_b[t * 16 + m];

        const unsigned short* gw = (const unsigned short*)gwb;
        #pragma unroll
        for (int t = 0; t < 8; ++t) {
            f32x4 c = {0.f, 0.f, 0.f, 0.f};
            // B[k = quad*8+j][n = lane&15] = gate_w[n_abs][k] -> contiguous row read
            const unsigned short* bp = gw + (size_t)(t * 16 + m) * CH + quad * 8;
            #pragma unroll
            for (int kk = 0; kk < 4; ++kk) {
                bf16x8 bfrag = *(const bf16x8*)(bp + kk * 32);
                c = __builtin_amdgcn_mfma_f32_16x16x32_bf16(afrag[kk], bfrag, c, 0, 0, 0);
            }
            // D: col = lane&15 (out channel), row = quad*4 + reg (node within wave's 16)
            #pragma unroll
            for (int reg = 0; reg < 4; ++reg) {
                const int r = wave * 16 + quad * 4 + reg;
                const int col = t * 16 + m;
                const float sp = spiral[r * PAD_ROW + col];
                spiral[r * PAD_ROW + col] = sp * (c[reg] + gb[t]);
            }
        }
    }
    __syncthreads();

    // ---- Phase 3: coalesced FP32 store ----
    {
        #pragma unroll
        for (int p = 0; p < 8; ++p) {
            const int seg = p * 256 + tid;      // 2048 segments of 4 floats
            const int row = seg >> 5;
            const int c4 = (seg & 31) * 4;
            const int node = node0 + row;
            if (node < N_NODES) {
                float4 v = *(const float4*)(spiral + row * PAD_ROW + c4);
                *(float4*)(out + ((size_t)b * N_NODES + node) * CH + c4) = v;
            }
        }
    }
}

// ---------------- Fallback: proven fp32-gather kernel (Round 5) ----------------
__global__ __launch_bounds__(256) void gated_spiral_kernel(
    const float* __restrict__ x,
    const int* __restrict__ indices,
    const float* __restrict__ weight,
    const float* __restrict__ gate_w,
    const float* __restrict__ gate_b,
    float* __restrict__ out)
{
    __shared__ float spiral[TILE * PAD_ROW];

    const int tile = blockIdx.x;
    const int b = blockIdx.y;
    const int tid = threadIdx.x;
    const int node0 = tile * TILE;

    const float* xb = x + (size_t)b * N_NODES * CH;

    {
        const int v = node0 + (tid >> 2);
        const int vc = v < N_NODES ? v : N_NODES - 1;
        const int q = tid & 3;

        int   idxv[SEQ];
        float wf[SEQ];
        const int*   ip = indices + (size_t)vc * SEQ;
        const float* wp = weight  + (size_t)vc * SEQ;
        #pragma unroll
        for (int s = 0; s < SEQ; ++s) {
            int t = ip[s];
            t = t < 0 ? 0 : t;
            idxv[s] = t >= N_NODES ? N_NODES - 1 : t;
            wf[s] = wp[s];
        }

        float acc[32];
        #pragma unroll
        for (int i = 0; i < 32; ++i) acc[i] = 0.f;

        #pragma unroll
        for (int s = 0; s < SEQ; ++s) {
            const float* row = xb + (size_t)idxv[s] * CH + q * 4;
            const float ws = wf[s];
            #pragma unroll
            for (int j = 0; j < 8; ++j) {
                float4 d = *(const float4*)(row + j * 16);
                acc[j*4+0] += ws * d.x;
                acc[j*4+1] += ws * d.y;
                acc[j*4+2] += ws * d.z;
                acc[j*4+3] += ws * d.w;
            }
        }

        const int vl = tid >> 2;
        #pragma unroll
        for (int j = 0; j < 8; ++j)
            *(float4*)(spiral + vl * PAD_ROW + j * 16 + q * 4) =
                make_float4(acc[j*4+0], acc[j*4+1], acc[j*4+2], acc[j*4+3]);
    }
    __syncthreads();

    {
        const int wave = tid >> 6;
        const int lane = tid & 63;
        const int m = lane & 15;
        const int quad = lane >> 4;

        int arow_node = node0 + wave * 16 + m;
        if (arow_node >= N_NODES) arow_node = N_NODES - 1;
        const float* ap = xb + (size_t)arow_node * CH + quad * 8;

        bf16x8 afrag[4];
        #pragma unroll
        for (int kk = 0; kk < 4; ++kk) {
            float4 lo = *(const float4*)(ap + kk * 32);
            float4 hi = *(const float4*)(ap + kk * 32 + 4);
            union { bf16x8 v; __hip_bfloat16 h[8]; } af;
            af.h[0] = __float2bfloat16(lo.x); af.h[1] = __float2bfloat16(lo.y);
            af.h[2] = __float2bfloat16(lo.z); af.h[3] = __float2bfloat16(lo.w);
            af.h[4] = __float2bfloat16(hi.x); af.h[5] = __float2bfloat16(hi.y);
            af.h[6] = __float2bfloat16(hi.z); af.h[7] = __float2bfloat16(hi.w);
            afrag[kk] = af.v;
        }

        float gb[8];
        #pragma unroll
        for (int t = 0; t < 8; ++t)
            gb[t] = gate_b[t * 16 + m];

        #pragma unroll
        for (int t = 0; t < 8; ++t) {
            f32x4 c = {0.f, 0.f, 0.f, 0.f};
            const float* bp = gate_w + (size_t)(t * 16 + m) * CH + quad * 8;
            #pragma unroll
            for (int kk = 0; kk < 4; ++kk) {
                float4 lo = *(const float4*)(bp + kk * 32);
                float4 hi = *(const float4*)(bp + kk * 32 + 4);
                union { bf16x8 v; __hip_bfloat16 h[8]; } bf;
                bf.h[0] = __float2bfloat16(lo.x); bf.h[1] = __float2bfloat16(lo.y);
                bf.h[2] = __float2bfloat16(lo.z); bf.h[3] = __float2bfloat16(lo.w);
                bf.h[4] = __float2bfloat16(hi.x); bf.h[5] = __float2bfloat16(hi.y);
                bf.h[6] = __float2bfloat16(hi.z); bf.h[7] = __float2bfloat16(hi.w);
                c = __builtin_amdgcn_mfma_f32_16x16x32_bf16(afrag[kk], bf.v, c, 0, 0, 0);
            }
            #pragma unroll
            for (int reg = 0; reg < 4; ++reg) {
                const int r = wave * 16 + quad * 4 + reg;
                const int col = t * 16 + m;
                const float sp = spiral[r * PAD_ROW + col];
                spiral[r * PAD_ROW + col] = sp * (c[reg] + gb[t]);
            }
        }
    }
    __syncthreads();

    {
        #pragma unroll
        for (int p = 0; p < 8; ++p) {
            const int seg = p * 256 + tid;
            const int row = seg >> 5;
            const int c4 = (seg & 31) * 4;
            const int node = node0 + row;
            if (node < N_NODES) {
                float4 v = *(const float4*)(spiral + row * PAD_ROW + c4);
                *(float4*)(out + ((size_t)b * N_NODES + node) * CH + c4) = v;
            }
        }
    }
}

extern "C" void kernel_launch(void* const* d_in, const int* in_sizes, int n_in,
                              void* d_out, int out_size, void* d_ws, size_t ws_size,
                              hipStream_t stream) {
    const float* x       = (const float*)d_in[0];
    const int*   indices = (const int*)d_in[1];
    const float* weight  = (const float*)d_in[2];
    const float* gate_w  = (const float*)d_in[3];
    const float* gate_b  = (const float*)d_in[4];
    float*       out     = (float*)d_out;

    const size_t x_bf_bytes = (size_t)BS * N_NODES * CH * 2;   // 51,200,000
    const size_t gw_bf_bytes = (size_t)CH * CH * 2;            // 32,768
    dim3 grid((N_NODES + TILE - 1) / TILE, BS);

    if (ws_size >= x_bf_bytes + gw_bf_bytes) {
        __hip_bfloat16* xbuf = (__hip_bfloat16*)d_ws;
        __hip_bfloat16* gwb  = (__hip_bfloat16*)((char*)d_ws + x_bf_bytes);
        const size_t n8 = (size_t)BS * N_NODES * CH / 8;       // 3,200,000
        convert_kernel<<<dim3((unsigned)((n8 + 255) / 256)), dim3(256), 0, stream>>>(
            x, gate_w, xbuf, gwb);
        gated_spiral_bf16_kernel<<<grid, dim3(256), 0, stream>>>(
            xbuf, indices, weight, gwb, gate_b, out);
    } else {
        gated_spiral_kernel<<<grid, dim3(256), 0, stream>>>(
            x, indices, weight, gate_w, gate_b, out);
    }
}